// Round 8
// baseline (190.181 us; speedup 1.0000x reference)
//
#include <hip/hip_runtime.h>
#include <hip/hip_bf16.h>
#include <cstdint>

#define B_      2
#define L_      2048
#define DM_     1024
#define H_      16
#define DQ_     64
#define LN_EPS  1e-5f
#define QSCALE  0.1803368801111204f   // 0.125 * log2(e): P = exp2(Q'.K)

typedef unsigned short u16;
typedef unsigned int   u32;
typedef __attribute__((ext_vector_type(8)))  short short8;
typedef __attribute__((ext_vector_type(4)))  unsigned short u16x4;
typedef __attribute__((ext_vector_type(4)))  unsigned int   u32x4;
typedef __attribute__((ext_vector_type(4)))  float f32x4;
typedef __attribute__((ext_vector_type(16))) float f32x16;

__device__ __forceinline__ u16 f2b(float f) {
  __hip_bfloat16 h = __float2bfloat16(f);
  return *reinterpret_cast<u16*>(&h);
}
__device__ __forceinline__ u32 pk2(float lo, float hi) {
  return (u32)f2b(lo) | ((u32)f2b(hi) << 16);
}

// async global->LDS, 16B per lane. lds ptr wave-uniform; data at lds+lane*16.
__device__ __forceinline__ void gl_lds16(const void* g, void* l) {
  auto gp = reinterpret_cast<const __attribute__((address_space(1))) unsigned int*>(
      reinterpret_cast<uintptr_t>(g));
  auto lp = reinterpret_cast<__attribute__((address_space(3))) unsigned int*>(
      reinterpret_cast<uintptr_t>(l));
  __builtin_amdgcn_global_load_lds(gp, lp, 16, 0, 0);
}

// raw barrier: no compiler-inserted vmcnt(0) drain (unlike __syncthreads).
__device__ __forceinline__ void bar() { asm volatile("s_barrier" ::: "memory"); }

// frag read from unpadded stride-64 tile with XOR swizzle (chunk ^= row&7).
__device__ __forceinline__ short8 frag8(const u16* base, int row, int lchunk) {
  return *(const short8*)(base + row * 64 + ((lchunk ^ (row & 7)) << 3));
}

// ---------------------------------------------------------------------------
// Prep (fused): cast x -> bf16; transpose/cast w_qkv -> wt; wo -> wot.
// ---------------------------------------------------------------------------
__global__ __launch_bounds__(256) void prep_all(
    const float* __restrict__ x, const float* __restrict__ wq,
    const float* __restrict__ wk, const float* __restrict__ wv,
    const float* __restrict__ wo, u16* __restrict__ xb,
    u16* __restrict__ wt, u16* __restrict__ wot) {
  __shared__ float Ls[64][65];
  const int t = threadIdx.x;
  const int bx = blockIdx.x;
  if (bx < 4096) {
    int i = bx * 256 + t;
    float4 v = ((const float4*)x)[i];
    u16x4 o = { f2b(v.x), f2b(v.y), f2b(v.z), f2b(v.w) };
    *(u16x4*)(xb + (size_t)i * 4) = o;
  } else if (bx < 4096 + 768) {
    int b2 = bx - 4096;
    int mt = b2 & 15, h = (b2 >> 4) & 15, wh = b2 >> 8;
    const float* in = ((wh == 0) ? wq : (wh == 1) ? wk : wv) + (size_t)h * DM_ * DQ_;
    #pragma unroll
    for (int i = 0; i < 16; ++i) {
      int idx = i * 256 + t, r = idx >> 6, c = idx & 63;
      Ls[r][c] = in[(size_t)(mt * 64 + r) * DQ_ + c];
    }
    __syncthreads();
    u16* outb = wt + (size_t)(wh * H_ + h) * DQ_ * DM_;
    #pragma unroll
    for (int i = 0; i < 16; ++i) {
      int idx = i * 256 + t, q = idx >> 6, mm = idx & 63;
      outb[(size_t)q * DM_ + mt * 64 + mm] = f2b(Ls[mm][q]);
    }
  } else {
    int b3 = bx - 4864;
    int mt = b3 & 15, kt = b3 >> 4;
    #pragma unroll
    for (int i = 0; i < 16; ++i) {
      int idx = i * 256 + t, r = idx >> 6, c = idx & 63;
      Ls[r][c] = wo[(size_t)(kt * 64 + r) * DM_ + mt * 64 + c];
    }
    __syncthreads();
    #pragma unroll
    for (int i = 0; i < 16; ++i) {
      int idx = i * 256 + t, mm = idx >> 6, kk = idx & 63;
      wot[(size_t)(mt * 64 + mm) * DM_ + kt * 64 + kk] = f2b(Ls[kk][mm]);
    }
  }
}

// ---------------------------------------------------------------------------
// Kernel 1: fused QKV GEMM [4096x1024]*[1024x3072], 256x256 tiles,
// counted-vmcnt schedule (R7, verified correct). Grid 192, XCD-swizzled.
// Q pre-scaled; V stored [b][h][d][l'] with key bits 2<->3 swapped.
// ---------------------------------------------------------------------------
__global__ __launch_bounds__(512) void qkv_big(const u16* __restrict__ xb,
    const u16* __restrict__ wt, u16* __restrict__ Q, u16* __restrict__ K,
    u16* __restrict__ Vtg) {
  const int raw = blockIdx.x;                  // 192 blocks
  const int swz = (raw & 7) * 24 + (raw >> 3); // chunked XCD swizzle (192%8==0)
  const int nt = swz >> 4, mt = swz & 15;      // nt 0..11, mt 0..15
  __shared__ __align__(16) u16 SH[65536];      // 128 KB
  u16* const A0 = SH;
  u16* const B0 = SH + 16384;
  u16* const A1 = SH + 32768;
  u16* const B1 = SH + 49152;
  const int t = threadIdx.x, w = t >> 6, lane = t & 63;
  const int lx = lane & 15, lq = lane >> 4;
  const int r8 = lane >> 3, lc = (lane & 7) ^ r8;
  const int row0 = mt * 256, n0 = nt * 256;
  const int wr = (w >> 2) * 128, wc = (w & 3) * 64;  // wave's 128x64 sub-tile

  const u16* gA = xb + (size_t)(row0 + w * 32 + r8) * DM_ + lc * 8;
  const u16* gB = wt + (size_t)(n0  + w * 32 + r8) * DM_ + lc * 8;
  const int lw = (w * 32) * 64;                // per-wave LDS slab base (u16)

  // prologue: tile0 (A+B, 8 loads) + A(1) slabs 0,1 (2 loads) = 10 in flight
  #pragma unroll
  for (int s = 0; s < 4; ++s)
    gl_lds16(gA + (size_t)s * 8 * DM_, A0 + lw + s * 8 * 64);
  #pragma unroll
  for (int s = 0; s < 4; ++s)
    gl_lds16(gB + (size_t)s * 8 * DM_, B0 + lw + s * 8 * 64);
  gl_lds16(gA + 64 + (size_t)0 * 8 * DM_, A1 + lw + 0 * 8 * 64);
  gl_lds16(gA + 64 + (size_t)1 * 8 * DM_, A1 + lw + 1 * 8 * 64);
  asm volatile("s_waitcnt vmcnt(2)" ::: "memory");   // tile 0 landed
  bar();

  f32x4 z = {0.f, 0.f, 0.f, 0.f};
  f32x4 acc[8][4];
  #pragma unroll
  for (int mf = 0; mf < 8; ++mf)
    #pragma unroll
    for (int nf = 0; nf < 4; ++nf) acc[mf][nf] = z;

  for (int tau = 0; tau < 16; ++tau) {
    const int d = tau & 1;
    u16* Ad = d ? A1 : A0;
    u16* Bd = d ? B1 : B0;
    u16* Ao = d ? A0 : A1;
    u16* Bo = d ? B0 : B1;
    const int t1 = (tau + 1 < 16) ? tau + 1 : 15;

    // ---- kh0 frags ----
    short8 af[8], bf[4];
    #pragma unroll
    for (int mf = 0; mf < 8; ++mf) af[mf] = frag8(Ad, wr + mf * 16 + lx, lq);
    #pragma unroll
    for (int nf = 0; nf < 4; ++nf) bf[nf] = frag8(Bd, wc + nf * 16 + lx, lq);

    // ---- prefetch tile tau+1 (6 loads -> other buffer) ----
    gl_lds16(gA + (size_t)t1 * 64 + (size_t)2 * 8 * DM_, Ao + lw + 2 * 8 * 64);
    gl_lds16(gA + (size_t)t1 * 64 + (size_t)3 * 8 * DM_, Ao + lw + 3 * 8 * 64);
    #pragma unroll
    for (int s = 0; s < 4; ++s)
      gl_lds16(gB + (size_t)t1 * 64 + (size_t)s * 8 * DM_, Bo + lw + s * 8 * 64);

    // ---- MFMA kh0 ----
    #pragma unroll
    for (int nf = 0; nf < 4; ++nf)
      #pragma unroll
      for (int mf = 0; mf < 8; ++mf)
        acc[mf][nf] = __builtin_amdgcn_mfma_f32_16x16x32_bf16(af[mf], bf[nf], acc[mf][nf], 0, 0, 0);

    // ---- kh1 frags + MFMA ----
    #pragma unroll
    for (int mf = 0; mf < 8; ++mf) af[mf] = frag8(Ad, wr + mf * 16 + lx, 4 | lq);
    #pragma unroll
    for (int nf = 0; nf < 4; ++nf) bf[nf] = frag8(Bd, wc + nf * 16 + lx, 4 | lq);
    #pragma unroll
    for (int nf = 0; nf < 4; ++nf)
      #pragma unroll
      for (int mf = 0; mf < 8; ++mf)
        acc[mf][nf] = __builtin_amdgcn_mfma_f32_16x16x32_bf16(af[mf], bf[nf], acc[mf][nf], 0, 0, 0);

    bar();   // all waves' LDS reads of buf[d] complete (lgkmcnt preceded MFMA)

    // stage A(tau+2) slabs 0,1 into buf[d].A (just freed)
    const int t2 = (tau + 2 < 16) ? tau + 2 : 15;
    gl_lds16(gA + (size_t)t2 * 64 + (size_t)0 * 8 * DM_, Ad + lw + 0 * 8 * 64);
    gl_lds16(gA + (size_t)t2 * 64 + (size_t)1 * 8 * DM_, Ad + lw + 1 * 8 * 64);

    asm volatile("s_waitcnt vmcnt(2)" ::: "memory");  // tile tau+1's 8 loads done
    bar();                                            // ...and visible to all waves
  }
  asm volatile("s_waitcnt vmcnt(0)" ::: "memory");    // drain clamp stragglers
  bar();

  // ---- epilogue: two 128-row passes through LDS (reuses SH) ----
  const int wh  = nt >> 2;                 // 0:Q 1:K 2:V
  const float oscale = (wh == 0) ? QSCALE : 1.0f;
  const int bb  = row0 >> 11, l0 = row0 & 2047;
  const int hd0 = (nt & 3) * 256;
  u16* Ep = SH;

  if (wh != 2) {
    u16* outp = (wh == 0) ? Q : K;
    #pragma unroll
    for (int mp = 0; mp < 2; ++mp) {
      if ((w >> 2) == mp) {
        #pragma unroll
        for (int mf = 0; mf < 8; ++mf)
          #pragma unroll
          for (int nf = 0; nf < 4; ++nf)
            #pragma unroll
            for (int r = 0; r < 4; ++r) {
              int l = mf * 16 + lq * 4 + r;                    // 0..127
              Ep[l * 264 + wc + nf * 16 + lx] = f2b(acc[mf][nf][r] * oscale);
            }
      }
      __syncthreads();
      #pragma unroll
      for (int hs = 0; hs < 4; ++hs) {
        const int hh = (hd0 >> 6) + hs;
        u16* gbase = outp + ((size_t)(bb * H_ + hh) * L_ + l0 + mp * 128) * DQ_;
        #pragma unroll
        for (int it = 0; it < 2; ++it) {
          int u = it * 512 + t;
          int l = u >> 3, ch = u & 7;
          *(uint4*)(gbase + (size_t)u * 8) = *(const uint4*)&Ep[l * 264 + hs * 64 + ch * 8];
        }
      }
      __syncthreads();
    }
  } else {
    // V: transpose to Ep[d][l'], l' = local l with bits 2<->3 swapped
    #pragma unroll
    for (int mp = 0; mp < 2; ++mp) {
      if ((w >> 2) == mp) {
        #pragma unroll
        for (int mf = 0; mf < 8; ++mf)
          #pragma unroll
          for (int nf = 0; nf < 4; ++nf) {
            int ll = mf * 16 + lq * 4;                         // 0..124
            int lp = (ll & ~12) | ((ll & 4) << 1) | ((ll & 8) >> 1);
            int dd = wc + nf * 16 + lx;                        // 0..255
            uint2 pv = { pk2(acc[mf][nf][0], acc[mf][nf][1]),
                         pk2(acc[mf][nf][2], acc[mf][nf][3]) };
            *(uint2*)&Ep[dd * 136 + lp] = pv;
          }
      }
      __syncthreads();
      #pragma unroll
      for (int it = 0; it < 8; ++it) {
        int v = it * 512 + t;
        int dloc = v >> 4, ch = v & 15;
        int hh = (hd0 + dloc) >> 6, ddg = (hd0 + dloc) & 63;
        u16* g = Vtg + ((size_t)(bb * H_ + hh) * DQ_ + ddg) * L_ + l0 + mp * 128 + ch * 8;
        *(uint4*)g = *(const uint4*)&Ep[dloc * 136 + ch * 8];
      }
      __syncthreads();
    }
  }
}

// ---------------------------------------------------------------------------
// Kernel 2: flash attention, KV-SPLIT: each (qt,b,h) computed by TWO blocks
// (hf = kv half). Grid 512 -> 2 blocks/CU (LDS 64KB each) = 4 waves/SIMD,
// doubling latency hiding on the QK->exp2->PV chain. Inner loop identical
// to the proven R2 code (16 tiles/half). No running max -> partials combine
// exactly: O = (O1+O2)/(l1+l2) in attn_combine. Partial O (f32) + rowsum
// to workspace. XCD swizzle keeps a group's K/V on one XCD (2MB, L2-res).
// ---------------------------------------------------------------------------
__global__ __launch_bounds__(512) void attn_mfma(const u16* __restrict__ Q,
    const u16* __restrict__ K, const u16* __restrict__ Vtg,
    float* __restrict__ Opart, float* __restrict__ lsum) {
  const int ord = blockIdx.x;                // 512 blocks
  const int r_  = ord & 7, s_ = ord >> 3;
  const int qt  = s_ & 7, hf = (s_ >> 3) & 1, ghi = s_ >> 4;
  const int grp = r_ + 8 * ghi;              // (b,h) group, constant per XCD
  const int h   = grp & 15, b = grp >> 4;
  __shared__ __align__(16) u16 Qs_[256 * 64];        // 32 KB
  __shared__ __align__(16) u16 Ks_[2][64 * 64];      // 16 KB
  __shared__ __align__(16) u16 Vt_[2][64 * 64];      // 16 KB
  const int t = threadIdx.x, w = t >> 6, lane = t & 63;
  const int c = lane & 31, lsel = lane >> 5;
  const int r8 = lane >> 3, lc = (lane & 7) ^ r8;
  const size_t bh  = (size_t)(b * H_ + h) * L_ * DQ_;
  const size_t bhv = (size_t)(b * H_ + h) * DQ_ * L_;
  const int kb0 = hf * (L_ / 2);             // this block's kv-range base

  // Q tile 256x64 via DMA: wave w stages rows [w*32, w*32+32)
  const u16* gQ = Q + bh + (size_t)(qt * 256 + w * 32 + r8) * DQ_ + lc * 8;
  #pragma unroll
  for (int i = 0; i < 4; ++i) gl_lds16(gQ + (size_t)i * 8 * DQ_, Qs_ + (w * 32 + i * 8) * 64);

  // wave w stages K rows [w*8, w*8+8) and Vt rows [w*8, w*8+8) of each tile
  const u16* gK = K   + bh  + (size_t)(kb0 + w * 8 + r8) * DQ_ + lc * 8;
  const u16* gV = Vtg + bhv + (size_t)(w * 8 + r8) * L_ + kb0 + lc * 8;

  // prime: K/V tile 0 into buffer 0
  gl_lds16(gK, Ks_[0] + w * 8 * 64);
  gl_lds16(gV, Vt_[0] + w * 8 * 64);
  __syncthreads();                          // Q (and tile 0) landed
  short8 qb[4];                             // B-frag: B[k=d][n=q], fixed
  #pragma unroll
  for (int km = 0; km < 4; ++km) qb[km] = frag8(Qs_, w * 32 + c, (km << 1) | lsel);

  f32x16 zz = {0.f,0.f,0.f,0.f,0.f,0.f,0.f,0.f,0.f,0.f,0.f,0.f,0.f,0.f,0.f,0.f};
  f32x16 oacc0 = zz, oacc1 = zz, lacc = zz;
  const short one_bf = (short)0x3F80;
  short8 ones = {one_bf, one_bf, one_bf, one_bf, one_bf, one_bf, one_bf, one_bf};

  for (int kt = 0; kt < 16; ++kt) {         // 16 tiles = this half's 1024 kv
    const int cur = kt & 1;
    __syncthreads();     // (a) DMA into buf[cur] drained  (b) prev reads of buf[cur] done

    if (kt + 1 < 16) {                      // prefetch tile kt+1 into buf[1-cur]
      const int nxt = 1 - cur;
      gl_lds16(gK + (size_t)(kt + 1) * 64 * DQ_, Ks_[nxt] + w * 8 * 64);
      gl_lds16(gV + (size_t)(kt + 1) * 64,       Vt_[nxt] + w * 8 * 64);
    }

    // S^T = K * Q'^T, then P = exp2(S') packed straight into A-frags (regs)
    u32x4 paw[4];
    #pragma unroll
    for (int kb = 0; kb < 2; ++kb) {
      f32x16 s = zz;
      #pragma unroll
      for (int km = 0; km < 4; ++km) {
        short8 ka = frag8(Ks_[cur], kb * 32 + c, (km << 1) | lsel);
        s = __builtin_amdgcn_mfma_f32_32x32x16_bf16(ka, qb[km], s, 0, 0, 0);
      }
      #pragma unroll
      for (int F = 0; F < 2; ++F) {
        u32x4 pw;
        #pragma unroll
        for (int i = 0; i < 4; ++i) {
          float p0 = __builtin_amdgcn_exp2f(s[8 * F + 2 * i]);
          float p1 = __builtin_amdgcn_exp2f(s[8 * F + 2 * i + 1]);
          pw[i] = __builtin_amdgcn_perm(__float_as_uint(p1), __float_as_uint(p0), 0x07060302u);
        }
        paw[2 * kb + F] = pw;
      }
    }

    // O += P V ; ones-column accumulates row sums (P from registers)
    #pragma unroll
    for (int km = 0; km < 4; ++km) {
      short8 pa  = *reinterpret_cast<const short8*>(&paw[km]);
      short8 vb0 = frag8(Vt_[cur], c,      (km << 1) | lsel);
      short8 vb1 = frag8(Vt_[cur], 32 + c, (km << 1) | lsel);
      oacc0 = __builtin_amdgcn_mfma_f32_32x32x16_bf16(pa, vb0, oacc0, 0, 0, 0);
      oacc1 = __builtin_amdgcn_mfma_f32_32x32x16_bf16(pa, vb1, oacc1, 0, 0, 0);
      lacc  = __builtin_amdgcn_mfma_f32_32x32x16_bf16(pa, ones, lacc, 0, 0, 0);
    }
  }

  // partial epilogue: O (f32) and rowsum to workspace; combined later
  const int qrow_base = qt * 256 + w * 32;
  float* Op = Opart + ((size_t)((hf * 2 + b) * H_ + h) * L_) * DQ_;
  float* Ls = lsum  +  (size_t)((hf * 2 + b) * H_ + h) * L_;
  #pragma unroll
  for (int r = 0; r < 16; ++r) {
    int qg = qrow_base + (r & 3) + 8 * (r >> 2) + 4 * lsel;
    Op[(size_t)qg * DQ_ + c]      = oacc0[r];
    Op[(size_t)qg * DQ_ + 32 + c] = oacc1[r];
    if (c == 0) Ls[qg] = lacc[r];
  }
}

// ---------------------------------------------------------------------------
// Kernel 2b: combine KV-halves: att = bf16((O1+O2) / (l1+l2)).
// ---------------------------------------------------------------------------
__global__ __launch_bounds__(256) void attn_combine(
    const float* __restrict__ Opart, const float* __restrict__ lsum,
    u16* __restrict__ att) {
  const int row = blockIdx.x;                // b*2048 + l
  const int b = row >> 11, l = row & 2047;
  const int t = threadIdx.x;
  const int h = t >> 4, dd = (t & 15) * 4;
  const size_t g0 = ((size_t)((0 + b) * H_ + h) * L_ + l);
  const size_t g1 = ((size_t)((2 + b) * H_ + h) * L_ + l);
  float4 a  = *(const float4*)(Opart + g0 * DQ_ + dd);
  float4 c4 = *(const float4*)(Opart + g1 * DQ_ + dd);
  float inv = 1.0f / (lsum[g0] + lsum[g1]);
  u16x4 o = { f2b((a.x + c4.x) * inv), f2b((a.y + c4.y) * inv),
              f2b((a.z + c4.z) * inv), f2b((a.w + c4.w) * inv) };
  *(u16x4*)(att + (size_t)row * DM_ + h * 64 + dd) = o;
}

// ---------------------------------------------------------------------------
// Kernel 3: output projection [4096x1024]*[1024x1024], 128x128 tiles,
// grid (8,32)=256 blocks = 1/CU. fp32 direct-store epilogue.
// ---------------------------------------------------------------------------
__global__ __launch_bounds__(256) void oproj_big(const u16* __restrict__ A,
    const u16* __restrict__ wot, float* __restrict__ out) {
  const int nt = blockIdx.x, mt = blockIdx.y;
  __shared__ __align__(16) u16 As_[128 * 64];
  __shared__ __align__(16) u16 Bs_[128 * 64];
  const int t = threadIdx.x, w = t >> 6, lane = t & 63;
  const int lx = lane & 15, lq = lane >> 4;
  const int row0 = mt * 128, n0 = nt * 128;
  const int r8 = lane >> 3, lc = (lane & 7) ^ r8;
  const int wr = (w >> 1) * 64, wc = (w & 1) * 64;   // wave's 64x64 sub-tile

  const u16* gA = A   + (size_t)(row0 + w * 32 + r8) * DM_ + lc * 8;
  const u16* gB = wot + (size_t)(n0  + w * 32 + r8) * DM_ + lc * 8;
  u16* lA = As_ + (w * 32) * 64;
  u16* lB = Bs_ + (w * 32) * 64;

  f32x4 z = {0.f, 0.f, 0.f, 0.f};
  f32x4 acc[4][4];
  #pragma unroll
  for (int mb = 0; mb < 4; ++mb)
    #pragma unroll
    for (int nb = 0; nb < 4; ++nb) acc[mb][nb] = z;

  for (int k0 = 0; k0 < DM_; k0 += 64) {
    #pragma unroll
    for (int i = 0; i < 4; ++i) {
      gl_lds16(gA + (size_t)i * 8 * DM_ + k0, lA + i * 8 * 64);
      gl_lds16(gB + (size_t)i * 8 * DM_ + k0, lB + i * 8 * 64);
    }
    __syncthreads();
    short8 af[4][2];
    #pragma unroll
    for (int mb = 0; mb < 4; ++mb)
      #pragma unroll
      for (int kh = 0; kh < 2; ++kh)
        af[mb][kh] = frag8(As_, wr + mb * 16 + lx, (kh << 2) | lq);
    #pragma unroll
    for (int nb = 0; nb < 4; ++nb) {
      short8 b0 = frag8(Bs_, wc + nb * 16 + lx, lq);
      short8 b1 = frag8(Bs_, wc + nb * 16 + lx, 4 | lq);
      #pragma unroll
      for (int mb = 0; mb < 4; ++mb) {
        acc[mb][nb] = __builtin_amdgcn_mfma_f32_16x16x32_bf16(af[mb][0], b0, acc[mb][nb], 0, 0, 0);
        acc[mb][nb] = __builtin_amdgcn_mfma_f32_16x16x32_bf16(af[mb][1], b1, acc[mb][nb], 0, 0, 0);
      }
    }
    __syncthreads();
  }
  #pragma unroll
  for (int mb = 0; mb < 4; ++mb)
    #pragma unroll
    for (int nb = 0; nb < 4; ++nb)
      #pragma unroll
      for (int r = 0; r < 4; ++r) {
        int row = row0 + wr + mb * 16 + lq * 4 + r;
        out[(size_t)row * DM_ + n0 + wc + nb * 16 + lx] = acc[mb][nb][r];
      }
}

// ---------------------------------------------------------------------------
// Kernel 4: residual + LayerNorm (in place on `out`).
// ---------------------------------------------------------------------------
__global__ __launch_bounds__(256) void resid_ln(
    const float* __restrict__ x, const float* __restrict__ gamma,
    const float* __restrict__ beta, float* __restrict__ out) {
  const int row = blockIdx.x;
  const int t   = threadIdx.x;
  const float4* xp = (const float4*)(x   + (size_t)row * DM_);
  float4*       yp = (float4*)      (out + (size_t)row * DM_);

  float4 xv = xp[t];
  float4 av = yp[t];
  float y0 = xv.x + av.x, y1 = xv.y + av.y, y2 = xv.z + av.z, y3 = xv.w + av.w;

  float s  = y0 + y1 + y2 + y3;
  float s2 = y0 * y0 + y1 * y1 + y2 * y2 + y3 * y3;
  #pragma unroll
  for (int off = 32; off > 0; off >>= 1) {
    s  += __shfl_xor(s,  off, 64);
    s2 += __shfl_xor(s2, off, 64);
  }
  __shared__ float red[8];
  const int wave = t >> 6, lane = t & 63;
  if (lane == 0) { red[wave] = s; red[4 + wave] = s2; }
  __syncthreads();
  s  = red[0] + red[1] + red[2] + red[3];
  s2 = red[4] + red[5] + red[6] + red[7];

  const float mean = s * (1.f / DM_);
  const float var  = s2 * (1.f / DM_) - mean * mean;
  const float inv  = rsqrtf(var + LN_EPS);

  const float4 g  = ((const float4*)gamma)[t];
  const float4 bt = ((const float4*)beta)[t];
  float4 r;
  r.x = (y0 - mean) * inv * g.x + bt.x;
  r.y = (y1 - mean) * inv * g.y + bt.y;
  r.z = (y2 - mean) * inv * g.z + bt.z;
  r.w = (y3 - mean) * inv * g.w + bt.w;
  yp[t] = r;
}

// ---------------------------------------------------------------------------
extern "C" void kernel_launch(void* const* d_in, const int* in_sizes, int n_in,
                              void* d_out, int out_size, void* d_ws, size_t ws_size,
                              hipStream_t stream) {
  const float* x     = (const float*)d_in[0];
  const float* wq    = (const float*)d_in[1];
  const float* wk    = (const float*)d_in[2];
  const float* wv    = (const float*)d_in[3];
  const float* wo    = (const float*)d_in[4];
  const float* gamma = (const float*)d_in[5];
  const float* beta  = (const float*)d_in[6];
  float* out = (float*)d_out;

  char* ws = (char*)d_ws;
  u16* xb   = (u16*)ws;                          // [ 0, 8) MB  [4096][1024]
  u16* Qb   = (u16*)(ws + ((size_t)8  << 20));   // [ 8,16) MB  [b][h][l][d]  (pre-scaled)
  u16* Kb   = (u16*)(ws + ((size_t)16 << 20));   // [16,24) MB  [b][h][l][d]
  u16* Vtg  = (u16*)(ws + ((size_t)24 << 20));   // [24,32) MB  [b][h][d][l'] (transposed, key-permuted)
  u16* wt   = (u16*)(ws + ((size_t)32 << 20));   // [32,38) MB  [3][h][q][m] = [3072][1024]
  u16* wot  = (u16*)(ws + ((size_t)38 << 20));   // [38,40) MB  [m][h*64+q]  = [1024][1024]
  u16* att  = (u16*)(ws + ((size_t)40 << 20));   // [40,48) MB  [b*l][h*64+d]
  float* Op = (float*)(ws + ((size_t)64 << 20)); // [64, 96) MB [hf][b][h][l][d] f32
  float* Ls = (float*)(ws + ((size_t)100 << 20));// [100,100.5) [hf][b][h][l] f32

  prep_all    <<<5120, 256, 0, stream>>>(x, wq, wk, wv, wo, xb, wt, wot);
  qkv_big     <<<192, 512, 0, stream>>>(xb, wt, Qb, Kb, Vtg);
  attn_mfma   <<<512, 512, 0, stream>>>(Qb, Kb, Vtg, Op, Ls);
  attn_combine<<<B_ * L_, 256, 0, stream>>>(Op, Ls, att);
  oproj_big   <<<dim3(8, 32), 256, 0, stream>>>(att, wot, out);
  resid_ln    <<<B_ * L_, 256, 0, stream>>>(x, gamma, beta, out);
}

// Round 9
// 183.102 us; speedup vs baseline: 1.0387x; 1.0387x over previous
//
#include <hip/hip_runtime.h>
#include <hip/hip_bf16.h>
#include <cstdint>

#define B_      2
#define L_      2048
#define DM_     1024
#define H_      16
#define DQ_     64
#define LN_EPS  1e-5f
#define QSCALE  0.1803368801111204f   // 0.125 * log2(e): P = exp2(Q'.K)

typedef unsigned short u16;
typedef unsigned int   u32;
typedef __attribute__((ext_vector_type(8)))  short short8;
typedef __attribute__((ext_vector_type(4)))  unsigned short u16x4;
typedef __attribute__((ext_vector_type(4)))  unsigned int   u32x4;
typedef __attribute__((ext_vector_type(4)))  float f32x4;
typedef __attribute__((ext_vector_type(16))) float f32x16;

__device__ __forceinline__ u16 f2b(float f) {
  __hip_bfloat16 h = __float2bfloat16(f);
  return *reinterpret_cast<u16*>(&h);
}
__device__ __forceinline__ u32 pk2(float lo, float hi) {
  return (u32)f2b(lo) | ((u32)f2b(hi) << 16);
}

// async global->LDS, 16B per lane. lds ptr wave-uniform; data at lds+lane*16.
__device__ __forceinline__ void gl_lds16(const void* g, void* l) {
  auto gp = reinterpret_cast<const __attribute__((address_space(1))) unsigned int*>(
      reinterpret_cast<uintptr_t>(g));
  auto lp = reinterpret_cast<__attribute__((address_space(3))) unsigned int*>(
      reinterpret_cast<uintptr_t>(l));
  __builtin_amdgcn_global_load_lds(gp, lp, 16, 0, 0);
}

// raw barrier: no compiler-inserted vmcnt(0) drain (unlike __syncthreads).
__device__ __forceinline__ void bar() { asm volatile("s_barrier" ::: "memory"); }

// frag read from unpadded stride-64 tile with XOR swizzle (chunk ^= row&7).
__device__ __forceinline__ short8 frag8(const u16* base, int row, int lchunk) {
  return *(const short8*)(base + row * 64 + ((lchunk ^ (row & 7)) << 3));
}

// ---------------------------------------------------------------------------
// Prep (fused): cast x -> bf16; transpose/cast w_qkv -> wt; wo -> wot.
// ---------------------------------------------------------------------------
__global__ __launch_bounds__(256) void prep_all(
    const float* __restrict__ x, const float* __restrict__ wq,
    const float* __restrict__ wk, const float* __restrict__ wv,
    const float* __restrict__ wo, u16* __restrict__ xb,
    u16* __restrict__ wt, u16* __restrict__ wot) {
  __shared__ float Ls[64][65];
  const int t = threadIdx.x;
  const int bx = blockIdx.x;
  if (bx < 4096) {
    int i = bx * 256 + t;
    float4 v = ((const float4*)x)[i];
    u16x4 o = { f2b(v.x), f2b(v.y), f2b(v.z), f2b(v.w) };
    *(u16x4*)(xb + (size_t)i * 4) = o;
  } else if (bx < 4096 + 768) {
    int b2 = bx - 4096;
    int mt = b2 & 15, h = (b2 >> 4) & 15, wh = b2 >> 8;
    const float* in = ((wh == 0) ? wq : (wh == 1) ? wk : wv) + (size_t)h * DM_ * DQ_;
    #pragma unroll
    for (int i = 0; i < 16; ++i) {
      int idx = i * 256 + t, r = idx >> 6, c = idx & 63;
      Ls[r][c] = in[(size_t)(mt * 64 + r) * DQ_ + c];
    }
    __syncthreads();
    u16* outb = wt + (size_t)(wh * H_ + h) * DQ_ * DM_;
    #pragma unroll
    for (int i = 0; i < 16; ++i) {
      int idx = i * 256 + t, q = idx >> 6, mm = idx & 63;
      outb[(size_t)q * DM_ + mt * 64 + mm] = f2b(Ls[mm][q]);
    }
  } else {
    int b3 = bx - 4864;
    int mt = b3 & 15, kt = b3 >> 4;
    #pragma unroll
    for (int i = 0; i < 16; ++i) {
      int idx = i * 256 + t, r = idx >> 6, c = idx & 63;
      Ls[r][c] = wo[(size_t)(kt * 64 + r) * DM_ + mt * 64 + c];
    }
    __syncthreads();
    #pragma unroll
    for (int i = 0; i < 16; ++i) {
      int idx = i * 256 + t, mm = idx >> 6, kk = idx & 63;
      wot[(size_t)(mt * 64 + mm) * DM_ + kt * 64 + kk] = f2b(Ls[kk][mm]);
    }
  }
}

// ---------------------------------------------------------------------------
// Kernel 1: fused QKV GEMM [4096x1024]*[1024x3072], 256x256 tiles,
// counted-vmcnt schedule (R7, verified correct). Grid 192, XCD-swizzled.
// Q pre-scaled; V stored [b][h][d][l'] with key bits 2<->3 swapped.
// ---------------------------------------------------------------------------
__global__ __launch_bounds__(512) void qkv_big(const u16* __restrict__ xb,
    const u16* __restrict__ wt, u16* __restrict__ Q, u16* __restrict__ K,
    u16* __restrict__ Vtg) {
  const int raw = blockIdx.x;                  // 192 blocks
  const int swz = (raw & 7) * 24 + (raw >> 3); // chunked XCD swizzle (192%8==0)
  const int nt = swz >> 4, mt = swz & 15;      // nt 0..11, mt 0..15
  __shared__ __align__(16) u16 SH[65536];      // 128 KB
  u16* const A0 = SH;
  u16* const B0 = SH + 16384;
  u16* const A1 = SH + 32768;
  u16* const B1 = SH + 49152;
  const int t = threadIdx.x, w = t >> 6, lane = t & 63;
  const int lx = lane & 15, lq = lane >> 4;
  const int r8 = lane >> 3, lc = (lane & 7) ^ r8;
  const int row0 = mt * 256, n0 = nt * 256;
  const int wr = (w >> 2) * 128, wc = (w & 3) * 64;  // wave's 128x64 sub-tile

  const u16* gA = xb + (size_t)(row0 + w * 32 + r8) * DM_ + lc * 8;
  const u16* gB = wt + (size_t)(n0  + w * 32 + r8) * DM_ + lc * 8;
  const int lw = (w * 32) * 64;                // per-wave LDS slab base (u16)

  // prologue: tile0 (A+B, 8 loads) + A(1) slabs 0,1 (2 loads) = 10 in flight
  #pragma unroll
  for (int s = 0; s < 4; ++s)
    gl_lds16(gA + (size_t)s * 8 * DM_, A0 + lw + s * 8 * 64);
  #pragma unroll
  for (int s = 0; s < 4; ++s)
    gl_lds16(gB + (size_t)s * 8 * DM_, B0 + lw + s * 8 * 64);
  gl_lds16(gA + 64 + (size_t)0 * 8 * DM_, A1 + lw + 0 * 8 * 64);
  gl_lds16(gA + 64 + (size_t)1 * 8 * DM_, A1 + lw + 1 * 8 * 64);
  asm volatile("s_waitcnt vmcnt(2)" ::: "memory");   // tile 0 landed
  bar();

  f32x4 z = {0.f, 0.f, 0.f, 0.f};
  f32x4 acc[8][4];
  #pragma unroll
  for (int mf = 0; mf < 8; ++mf)
    #pragma unroll
    for (int nf = 0; nf < 4; ++nf) acc[mf][nf] = z;

  for (int tau = 0; tau < 16; ++tau) {
    const int d = tau & 1;
    u16* Ad = d ? A1 : A0;
    u16* Bd = d ? B1 : B0;
    u16* Ao = d ? A0 : A1;
    u16* Bo = d ? B0 : B1;
    const int t1 = (tau + 1 < 16) ? tau + 1 : 15;

    // ---- kh0 frags ----
    short8 af[8], bf[4];
    #pragma unroll
    for (int mf = 0; mf < 8; ++mf) af[mf] = frag8(Ad, wr + mf * 16 + lx, lq);
    #pragma unroll
    for (int nf = 0; nf < 4; ++nf) bf[nf] = frag8(Bd, wc + nf * 16 + lx, lq);

    // ---- prefetch tile tau+1 (6 loads -> other buffer) ----
    gl_lds16(gA + (size_t)t1 * 64 + (size_t)2 * 8 * DM_, Ao + lw + 2 * 8 * 64);
    gl_lds16(gA + (size_t)t1 * 64 + (size_t)3 * 8 * DM_, Ao + lw + 3 * 8 * 64);
    #pragma unroll
    for (int s = 0; s < 4; ++s)
      gl_lds16(gB + (size_t)t1 * 64 + (size_t)s * 8 * DM_, Bo + lw + s * 8 * 64);

    // ---- MFMA kh0 ----
    #pragma unroll
    for (int nf = 0; nf < 4; ++nf)
      #pragma unroll
      for (int mf = 0; mf < 8; ++mf)
        acc[mf][nf] = __builtin_amdgcn_mfma_f32_16x16x32_bf16(af[mf], bf[nf], acc[mf][nf], 0, 0, 0);

    // ---- kh1 frags + MFMA ----
    #pragma unroll
    for (int mf = 0; mf < 8; ++mf) af[mf] = frag8(Ad, wr + mf * 16 + lx, 4 | lq);
    #pragma unroll
    for (int nf = 0; nf < 4; ++nf) bf[nf] = frag8(Bd, wc + nf * 16 + lx, 4 | lq);
    #pragma unroll
    for (int nf = 0; nf < 4; ++nf)
      #pragma unroll
      for (int mf = 0; mf < 8; ++mf)
        acc[mf][nf] = __builtin_amdgcn_mfma_f32_16x16x32_bf16(af[mf], bf[nf], acc[mf][nf], 0, 0, 0);

    bar();   // all waves' LDS reads of buf[d] complete (lgkmcnt preceded MFMA)

    // stage A(tau+2) slabs 0,1 into buf[d].A (just freed)
    const int t2 = (tau + 2 < 16) ? tau + 2 : 15;
    gl_lds16(gA + (size_t)t2 * 64 + (size_t)0 * 8 * DM_, Ad + lw + 0 * 8 * 64);
    gl_lds16(gA + (size_t)t2 * 64 + (size_t)1 * 8 * DM_, Ad + lw + 1 * 8 * 64);

    asm volatile("s_waitcnt vmcnt(2)" ::: "memory");  // tile tau+1's 8 loads done
    bar();                                            // ...and visible to all waves
  }
  asm volatile("s_waitcnt vmcnt(0)" ::: "memory");    // drain clamp stragglers
  bar();

  // ---- epilogue: two 128-row passes through LDS (reuses SH) ----
  const int wh  = nt >> 2;                 // 0:Q 1:K 2:V
  const float oscale = (wh == 0) ? QSCALE : 1.0f;
  const int bb  = row0 >> 11, l0 = row0 & 2047;
  const int hd0 = (nt & 3) * 256;
  u16* Ep = SH;

  if (wh != 2) {
    u16* outp = (wh == 0) ? Q : K;
    #pragma unroll
    for (int mp = 0; mp < 2; ++mp) {
      if ((w >> 2) == mp) {
        #pragma unroll
        for (int mf = 0; mf < 8; ++mf)
          #pragma unroll
          for (int nf = 0; nf < 4; ++nf)
            #pragma unroll
            for (int r = 0; r < 4; ++r) {
              int l = mf * 16 + lq * 4 + r;                    // 0..127
              Ep[l * 264 + wc + nf * 16 + lx] = f2b(acc[mf][nf][r] * oscale);
            }
      }
      __syncthreads();
      #pragma unroll
      for (int hs = 0; hs < 4; ++hs) {
        const int hh = (hd0 >> 6) + hs;
        u16* gbase = outp + ((size_t)(bb * H_ + hh) * L_ + l0 + mp * 128) * DQ_;
        #pragma unroll
        for (int it = 0; it < 2; ++it) {
          int u = it * 512 + t;
          int l = u >> 3, ch = u & 7;
          *(uint4*)(gbase + (size_t)u * 8) = *(const uint4*)&Ep[l * 264 + hs * 64 + ch * 8];
        }
      }
      __syncthreads();
    }
  } else {
    // V: transpose to Ep[d][l'], l' = local l with bits 2<->3 swapped
    #pragma unroll
    for (int mp = 0; mp < 2; ++mp) {
      if ((w >> 2) == mp) {
        #pragma unroll
        for (int mf = 0; mf < 8; ++mf)
          #pragma unroll
          for (int nf = 0; nf < 4; ++nf) {
            int ll = mf * 16 + lq * 4;                         // 0..124
            int lp = (ll & ~12) | ((ll & 4) << 1) | ((ll & 8) >> 1);
            int dd = wc + nf * 16 + lx;                        // 0..255
            uint2 pv = { pk2(acc[mf][nf][0], acc[mf][nf][1]),
                         pk2(acc[mf][nf][2], acc[mf][nf][3]) };
            *(uint2*)&Ep[dd * 136 + lp] = pv;
          }
      }
      __syncthreads();
      #pragma unroll
      for (int it = 0; it < 8; ++it) {
        int v = it * 512 + t;
        int dloc = v >> 4, ch = v & 15;
        int hh = (hd0 + dloc) >> 6, ddg = (hd0 + dloc) & 63;
        u16* g = Vtg + ((size_t)(bb * H_ + hh) * DQ_ + ddg) * L_ + l0 + mp * 128 + ch * 8;
        *(uint4*)g = *(const uint4*)&Ep[dloc * 136 + ch * 8];
      }
      __syncthreads();
    }
  }
}

// ---------------------------------------------------------------------------
// Kernel 2: flash attention. R2-proven config (best measured): Q-tile 256
// via 8-wave blocks (32 q-rows/wave), 64-row K/V double-buffered DMA
// prefetch, ONE barrier per K-tile, P in registers, lacc-MFMA rowsum,
// bijective XCD swizzle (K/V 2MB/XCD resident in L2 -> FETCH ~12MB).
// Issue-rate-bound at ~78% combined MFMA+VALU slot utilization (R8 test:
// doubling occupancy changed nothing) — do not graft schedule tweaks.
// ---------------------------------------------------------------------------
__global__ __launch_bounds__(512) void attn_mfma(const u16* __restrict__ Q,
    const u16* __restrict__ K, const u16* __restrict__ Vtg, u16* __restrict__ att) {
  const int ord = blockIdx.x;
  const int r_  = ord & 7, s_ = ord >> 3;
  const int qt  = s_ & 7, ghi = s_ >> 3;
  const int grp = r_ + 8 * ghi;            // (b,h) group, constant per XCD
  const int h   = grp & 15, b = grp >> 4;
  __shared__ __align__(16) u16 Qs_[256 * 64];        // 32 KB
  __shared__ __align__(16) u16 Ks_[2][64 * 64];      // 16 KB
  __shared__ __align__(16) u16 Vt_[2][64 * 64];      // 16 KB
  const int t = threadIdx.x, w = t >> 6, lane = t & 63;
  const int c = lane & 31, lsel = lane >> 5;
  const int r8 = lane >> 3, lc = (lane & 7) ^ r8;
  const size_t bh  = (size_t)(b * H_ + h) * L_ * DQ_;
  const size_t bhv = (size_t)(b * H_ + h) * DQ_ * L_;

  // Q tile 256x64 via DMA: wave w stages rows [w*32, w*32+32)
  const u16* gQ = Q + bh + (size_t)(qt * 256 + w * 32 + r8) * DQ_ + lc * 8;
  #pragma unroll
  for (int i = 0; i < 4; ++i) gl_lds16(gQ + (size_t)i * 8 * DQ_, Qs_ + (w * 32 + i * 8) * 64);

  // wave w stages K rows [w*8, w*8+8) and Vt rows [w*8, w*8+8) of each tile
  const u16* gK = K   + bh  + (size_t)(w * 8 + r8) * DQ_ + lc * 8;
  const u16* gV = Vtg + bhv + (size_t)(w * 8 + r8) * L_  + lc * 8;

  // prime: K/V tile 0 into buffer 0
  gl_lds16(gK, Ks_[0] + w * 8 * 64);
  gl_lds16(gV, Vt_[0] + w * 8 * 64);
  __syncthreads();                          // Q (and tile 0) landed
  short8 qb[4];                             // B-frag: B[k=d][n=q], fixed
  #pragma unroll
  for (int km = 0; km < 4; ++km) qb[km] = frag8(Qs_, w * 32 + c, (km << 1) | lsel);

  f32x16 zz = {0.f,0.f,0.f,0.f,0.f,0.f,0.f,0.f,0.f,0.f,0.f,0.f,0.f,0.f,0.f,0.f};
  f32x16 oacc0 = zz, oacc1 = zz, lacc = zz;
  const short one_bf = (short)0x3F80;
  short8 ones = {one_bf, one_bf, one_bf, one_bf, one_bf, one_bf, one_bf, one_bf};

  for (int kt = 0; kt < L_ / 64; ++kt) {
    const int cur = kt & 1;
    __syncthreads();     // (a) DMA into buf[cur] drained  (b) prev reads of buf[cur] done

    if (kt + 1 < L_ / 64) {                 // prefetch tile kt+1 into buf[1-cur]
      const int nxt = 1 - cur;
      gl_lds16(gK + (size_t)(kt + 1) * 64 * DQ_, Ks_[nxt] + w * 8 * 64);
      gl_lds16(gV + (size_t)(kt + 1) * 64,       Vt_[nxt] + w * 8 * 64);
    }

    // S^T = K * Q'^T, then P = exp2(S') packed straight into A-frags (regs)
    u32x4 paw[4];
    #pragma unroll
    for (int kb = 0; kb < 2; ++kb) {
      f32x16 s = zz;
      #pragma unroll
      for (int km = 0; km < 4; ++km) {
        short8 ka = frag8(Ks_[cur], kb * 32 + c, (km << 1) | lsel);
        s = __builtin_amdgcn_mfma_f32_32x32x16_bf16(ka, qb[km], s, 0, 0, 0);
      }
      #pragma unroll
      for (int F = 0; F < 2; ++F) {
        u32x4 pw;
        #pragma unroll
        for (int i = 0; i < 4; ++i) {
          float p0 = __builtin_amdgcn_exp2f(s[8 * F + 2 * i]);
          float p1 = __builtin_amdgcn_exp2f(s[8 * F + 2 * i + 1]);
          pw[i] = __builtin_amdgcn_perm(__float_as_uint(p1), __float_as_uint(p0), 0x07060302u);
        }
        paw[2 * kb + F] = pw;
      }
    }

    // O += P V ; ones-column accumulates row sums (P from registers)
    #pragma unroll
    for (int km = 0; km < 4; ++km) {
      short8 pa  = *reinterpret_cast<const short8*>(&paw[km]);
      short8 vb0 = frag8(Vt_[cur], c,      (km << 1) | lsel);
      short8 vb1 = frag8(Vt_[cur], 32 + c, (km << 1) | lsel);
      oacc0 = __builtin_amdgcn_mfma_f32_32x32x16_bf16(pa, vb0, oacc0, 0, 0, 0);
      oacc1 = __builtin_amdgcn_mfma_f32_32x32x16_bf16(pa, vb1, oacc1, 0, 0, 0);
      lacc  = __builtin_amdgcn_mfma_f32_32x32x16_bf16(pa, ones, lacc, 0, 0, 0);
    }
  }

  const int qrow_base = qt * 256 + w * 32;
  #pragma unroll
  for (int r = 0; r < 16; ++r) {
    int qr = (r & 3) + 8 * (r >> 2) + 4 * lsel;
    float inv = 1.0f / lacc[r];
    size_t base = (size_t)(b * L_ + qrow_base + qr) * DM_ + h * DQ_;
    att[base + c]      = f2b(oacc0[r] * inv);
    att[base + 32 + c] = f2b(oacc1[r] * inv);
  }
}

// ---------------------------------------------------------------------------
// Kernel 3: output projection [4096x1024]*[1024x1024], 128x128 tiles,
// grid (8,32)=256 blocks = 1/CU. fp32 direct-store epilogue.
// ---------------------------------------------------------------------------
__global__ __launch_bounds__(256) void oproj_big(const u16* __restrict__ A,
    const u16* __restrict__ wot, float* __restrict__ out) {
  const int nt = blockIdx.x, mt = blockIdx.y;
  __shared__ __align__(16) u16 As_[128 * 64];
  __shared__ __align__(16) u16 Bs_[128 * 64];
  const int t = threadIdx.x, w = t >> 6, lane = t & 63;
  const int lx = lane & 15, lq = lane >> 4;
  const int row0 = mt * 128, n0 = nt * 128;
  const int r8 = lane >> 3, lc = (lane & 7) ^ r8;
  const int wr = (w >> 1) * 64, wc = (w & 1) * 64;   // wave's 64x64 sub-tile

  const u16* gA = A   + (size_t)(row0 + w * 32 + r8) * DM_ + lc * 8;
  const u16* gB = wot + (size_t)(n0  + w * 32 + r8) * DM_ + lc * 8;
  u16* lA = As_ + (w * 32) * 64;
  u16* lB = Bs_ + (w * 32) * 64;

  f32x4 z = {0.f, 0.f, 0.f, 0.f};
  f32x4 acc[4][4];
  #pragma unroll
  for (int mb = 0; mb < 4; ++mb)
    #pragma unroll
    for (int nb = 0; nb < 4; ++nb) acc[mb][nb] = z;

  for (int k0 = 0; k0 < DM_; k0 += 64) {
    #pragma unroll
    for (int i = 0; i < 4; ++i) {
      gl_lds16(gA + (size_t)i * 8 * DM_ + k0, lA + i * 8 * 64);
      gl_lds16(gB + (size_t)i * 8 * DM_ + k0, lB + i * 8 * 64);
    }
    __syncthreads();
    short8 af[4][2];
    #pragma unroll
    for (int mb = 0; mb < 4; ++mb)
      #pragma unroll
      for (int kh = 0; kh < 2; ++kh)
        af[mb][kh] = frag8(As_, wr + mb * 16 + lx, (kh << 2) | lq);
    #pragma unroll
    for (int nb = 0; nb < 4; ++nb) {
      short8 b0 = frag8(Bs_, wc + nb * 16 + lx, lq);
      short8 b1 = frag8(Bs_, wc + nb * 16 + lx, 4 | lq);
      #pragma unroll
      for (int mb = 0; mb < 4; ++mb) {
        acc[mb][nb] = __builtin_amdgcn_mfma_f32_16x16x32_bf16(af[mb][0], b0, acc[mb][nb], 0, 0, 0);
        acc[mb][nb] = __builtin_amdgcn_mfma_f32_16x16x32_bf16(af[mb][1], b1, acc[mb][nb], 0, 0, 0);
      }
    }
    __syncthreads();
  }
  #pragma unroll
  for (int mb = 0; mb < 4; ++mb)
    #pragma unroll
    for (int nb = 0; nb < 4; ++nb)
      #pragma unroll
      for (int r = 0; r < 4; ++r) {
        int row = row0 + wr + mb * 16 + lq * 4 + r;
        out[(size_t)row * DM_ + n0 + wc + nb * 16 + lx] = acc[mb][nb][r];
      }
}

// ---------------------------------------------------------------------------
// Kernel 4: residual + LayerNorm (in place on `out`).
// ---------------------------------------------------------------------------
__global__ __launch_bounds__(256) void resid_ln(
    const float* __restrict__ x, const float* __restrict__ gamma,
    const float* __restrict__ beta, float* __restrict__ out) {
  const int row = blockIdx.x;
  const int t   = threadIdx.x;
  const float4* xp = (const float4*)(x   + (size_t)row * DM_);
  float4*       yp = (float4*)      (out + (size_t)row * DM_);

  float4 xv = xp[t];
  float4 av = yp[t];
  float y0 = xv.x + av.x, y1 = xv.y + av.y, y2 = xv.z + av.z, y3 = xv.w + av.w;

  float s  = y0 + y1 + y2 + y3;
  float s2 = y0 * y0 + y1 * y1 + y2 * y2 + y3 * y3;
  #pragma unroll
  for (int off = 32; off > 0; off >>= 1) {
    s  += __shfl_xor(s,  off, 64);
    s2 += __shfl_xor(s2, off, 64);
  }
  __shared__ float red[8];
  const int wave = t >> 6, lane = t & 63;
  if (lane == 0) { red[wave] = s; red[4 + wave] = s2; }
  __syncthreads();
  s  = red[0] + red[1] + red[2] + red[3];
  s2 = red[4] + red[5] + red[6] + red[7];

  const float mean = s * (1.f / DM_);
  const float var  = s2 * (1.f / DM_) - mean * mean;
  const float inv  = rsqrtf(var + LN_EPS);

  const float4 g  = ((const float4*)gamma)[t];
  const float4 bt = ((const float4*)beta)[t];
  float4 r;
  r.x = (y0 - mean) * inv * g.x + bt.x;
  r.y = (y1 - mean) * inv * g.y + bt.y;
  r.z = (y2 - mean) * inv * g.z + bt.z;
  r.w = (y3 - mean) * inv * g.w + bt.w;
  yp[t] = r;
}

// ---------------------------------------------------------------------------
extern "C" void kernel_launch(void* const* d_in, const int* in_sizes, int n_in,
                              void* d_out, int out_size, void* d_ws, size_t ws_size,
                              hipStream_t stream) {
  const float* x     = (const float*)d_in[0];
  const float* wq    = (const float*)d_in[1];
  const float* wk    = (const float*)d_in[2];
  const float* wv    = (const float*)d_in[3];
  const float* wo    = (const float*)d_in[4];
  const float* gamma = (const float*)d_in[5];
  const float* beta  = (const float*)d_in[6];
  float* out = (float*)d_out;

  char* ws = (char*)d_ws;
  u16* xb  = (u16*)ws;                          // [ 0, 8) MB  [4096][1024]
  u16* Qb  = (u16*)(ws + ((size_t)8  << 20));   // [ 8,16) MB  [b][h][l][d]  (pre-scaled)
  u16* Kb  = (u16*)(ws + ((size_t)16 << 20));   // [16,24) MB  [b][h][l][d]
  u16* Vtg = (u16*)(ws + ((size_t)24 << 20));   // [24,32) MB  [b][h][d][l'] (transposed, key-permuted)
  u16* wt  = (u16*)(ws + ((size_t)32 << 20));   // [32,38) MB  [3][h][q][m] = [3072][1024]
  u16* wot = (u16*)(ws + ((size_t)38 << 20));   // [38,40) MB  [m][h*64+q]  = [1024][1024]
  u16* att = (u16*)(ws + ((size_t)40 << 20));   // [40,48) MB  [b*l][h*64+d]

  prep_all <<<5120, 256, 0, stream>>>(x, wq, wk, wv, wo, xb, wt, wot);
  qkv_big  <<<192, 512, 0, stream>>>(xb, wt, Qb, Kb, Vtg);
  attn_mfma<<<256, 512, 0, stream>>>(Qb, Kb, Vtg, att);
  oproj_big<<<dim3(8, 32), 256, 0, stream>>>(att, wot, out);
  resid_ln <<<B_ * L_, 256, 0, stream>>>(x, gamma, beta, out);
}